// Round 3
// baseline (1375.388 us; speedup 1.0000x reference)
//
#include <hip/hip_runtime.h>
#include <hip/hip_bf16.h>
#include <hip/hip_fp16.h>

#define RN 4096
#define EN 131072
#define TN 1536
#define T2 768            // TN/2 sample-pairs per row
#define PN 256
#define NBOUNCE 12
#define NCHUNK 4
#define CPAIRS 192        // pairs per chunk = T2 / NCHUNK
// np.float32(np.log(1e-3))
#define LOG_GAMMA -6.90775528f
#define INV_SR (1.0f / 16000.0f)

// ---------------- CSR build ----------------

__global__ void hist_kernel(const int* __restrict__ row, int* __restrict__ cnt) {
    int e = blockIdx.x * blockDim.x + threadIdx.x;
    if (e < EN) atomicAdd(&cnt[row[e]], 1);
}

// single block, 1024 threads: exclusive scan of cnt[0..RN) -> off[0..RN], off[RN]=EN
__global__ void scan_kernel(const int* __restrict__ cnt, int* __restrict__ off,
                            int* __restrict__ cursor) {
    __shared__ int part[1024];
    int tid = threadIdx.x;
    int v0 = cnt[tid * 4 + 0], v1 = cnt[tid * 4 + 1];
    int v2 = cnt[tid * 4 + 2], v3 = cnt[tid * 4 + 3];
    part[tid] = v0 + v1 + v2 + v3;
    __syncthreads();
    for (int ofs = 1; ofs < 1024; ofs <<= 1) {
        int x = (tid >= ofs) ? part[tid - ofs] : 0;
        __syncthreads();
        part[tid] += x;
        __syncthreads();
    }
    int excl = (tid == 0) ? 0 : part[tid - 1];
    int o0 = excl, o1 = o0 + v0, o2 = o1 + v1, o3 = o2 + v2;
    off[tid * 4 + 0] = o0; cursor[tid * 4 + 0] = o0;
    off[tid * 4 + 1] = o1; cursor[tid * 4 + 1] = o1;
    off[tid * 4 + 2] = o2; cursor[tid * 4 + 2] = o2;
    off[tid * 4 + 3] = o3; cursor[tid * 4 + 3] = o3;
    if (tid == 1023) off[RN] = o3 + v3;
}

// per edge: compute kernel value, place (col|delay<<12, kern) into CSR slot
__global__ void scatter_kernel(const int* __restrict__ row, const int* __restrict__ col,
                               const int* __restrict__ rid, const int* __restrict__ delay,
                               const float* __restrict__ basis,
                               const float* __restrict__ absorption,
                               const float* __restrict__ scattering,
                               int* __restrict__ cursor,
                               int* __restrict__ packed, float* __restrict__ kernv) {
    int e = blockIdx.x * blockDim.x + threadIdx.x;
    if (e >= EN) return;
    int p = rid[e];
    float a = absorption[p];
    float s = scattering[p];
    float k = (1.0f - a) * (s * basis[e] + (1.0f - s) * basis[EN + e]);
    int r = row[e];
    int pos = atomicAdd(&cursor[r], 1);
    packed[pos] = col[e] | (delay[e] << 12);
    kernv[pos] = k;
}

// ---------------- init: cur = tot = half(x * window) ----------------

__global__ void init_kernel(const float* __restrict__ x, __half* __restrict__ cur,
                            __half* __restrict__ tot) {
    int g = blockIdx.x * blockDim.x + threadIdx.x;   // 8 elements per thread
    if (g >= RN * TN / 8) return;
    int t8 = g % (TN / 8);
    int tbase = t8 * 8;
    const float4 v0 = reinterpret_cast<const float4*>(x)[g * 2 + 0];
    const float4 v1 = reinterpret_cast<const float4*>(x)[g * 2 + 1];
    __half h[8];
    h[0] = __float2half(v0.x * __expf(LOG_GAMMA * (float)(tbase + 0) * INV_SR));
    h[1] = __float2half(v0.y * __expf(LOG_GAMMA * (float)(tbase + 1) * INV_SR));
    h[2] = __float2half(v0.z * __expf(LOG_GAMMA * (float)(tbase + 2) * INV_SR));
    h[3] = __float2half(v0.w * __expf(LOG_GAMMA * (float)(tbase + 3) * INV_SR));
    h[4] = __float2half(v1.x * __expf(LOG_GAMMA * (float)(tbase + 4) * INV_SR));
    h[5] = __float2half(v1.y * __expf(LOG_GAMMA * (float)(tbase + 5) * INV_SR));
    h[6] = __float2half(v1.z * __expf(LOG_GAMMA * (float)(tbase + 6) * INV_SR));
    h[7] = __float2half(v1.w * __expf(LOG_GAMMA * (float)(tbase + 7) * INV_SR));
    float4 packed = *reinterpret_cast<float4*>(h);
    reinterpret_cast<float4*>(cur)[g] = packed;
    reinterpret_cast<float4*>(tot)[g] = packed;
}

// ---------------- bounce ----------------
// Block = (row r, T-chunk c0 of 384 samples = 192 pairs), 192 threads, 1 pair/thread.
// grid index = r*4 + chunk so chunk <-> XCD via round-robin dispatch (L2 locality).
// nxt[r, t] = sum_e kern_e * cur[col_e, (t - d_e) mod T];  tot += nxt.

__global__ __launch_bounds__(192) void bounce_kernel(
        const __half* __restrict__ cur, __half* __restrict__ nxt, __half* __restrict__ tot,
        const int* __restrict__ off, const int* __restrict__ packed,
        const float* __restrict__ kernv) {
    int bid = blockIdx.x;
    int r = bid >> 2;
    int c0 = (bid & 3) * CPAIRS;           // pair-index base of this chunk
    int tid = threadIdx.x;
    int e0 = off[r], e1 = off[r + 1];
    float ax = 0.f, ay = 0.f;
    const uint* curu = (const uint*)cur;   // one uint = one sample pair
    __shared__ int   s_pk[192];
    __shared__ float s_kv[192];
    for (int base = e0; base < e1; base += 192) {
        int n = min(192, e1 - base);
        __syncthreads();
        if (tid < n) { s_pk[tid] = packed[base + tid]; s_kv[tid] = kernv[base + tid]; }
        __syncthreads();
        for (int j = 0; j < n; ++j) {
            // per-edge state is wave-uniform -> force into SGPRs
            int pk  = __builtin_amdgcn_readfirstlane(s_pk[j]);
            float k = __uint_as_float(__builtin_amdgcn_readfirstlane(__float_as_uint(s_kv[j])));
            int c = pk & 4095;
            int d = pk >> 12;
            const uint* rowp = curu + c * T2;   // SGPR base
            if (d & 1) {
                // need samples (2p+1, 2p+2): two dwords + realign
                int p = tid + (c0 - ((d + 1) >> 1) + T2);
                if (p >= T2) p -= T2;
                int p1 = p + 1;
                if (p1 >= T2) p1 -= T2;
                uint w0 = rowp[p];
                uint w1 = rowp[p1];
                uint v = __builtin_amdgcn_alignbit(w1, w0, 16);
                float2 fv = __half22float2(*reinterpret_cast<const __half2*>(&v));
                ax = fmaf(k, fv.x, ax);
                ay = fmaf(k, fv.y, ay);
            } else {
                int p = tid + (c0 - (d >> 1) + T2);
                if (p >= T2) p -= T2;
                uint v = rowp[p];
                float2 fv = __half22float2(*reinterpret_cast<const __half2*>(&v));
                ax = fmaf(k, fv.x, ax);
                ay = fmaf(k, fv.y, ay);
            }
        }
    }
    int tp = r * T2 + c0 + tid;
    reinterpret_cast<__half2*>(nxt)[tp] = __float22half2_rn(make_float2(ax, ay));
    float2 tf = __half22float2(reinterpret_cast<__half2*>(tot)[tp]);
    tf.x += ax; tf.y += ay;
    reinterpret_cast<__half2*>(tot)[tp] = __float22half2_rn(make_float2(tf.x, tf.y));
}

// ---------------- detection ----------------

__global__ void detect_kernel(const __half* __restrict__ tot, const float* __restrict__ w,
                              const int* __restrict__ dd, float* __restrict__ det) {
    int t = blockIdx.x * 256 + threadIdx.x;
    int r0 = blockIdx.y * 64;
    float acc = 0.f;
    for (int r = r0; r < r0 + 64; ++r) {
        int d = dd[r];
        int idx = t - d;
        if (idx < 0) idx += TN;
        acc = fmaf(w[r], __half2float(tot[r * TN + idx]), acc);
    }
    atomicAdd(&det[t], acc);
}

__global__ void final_kernel(const float* __restrict__ det, float* __restrict__ out) {
    int t = blockIdx.x * 256 + threadIdx.x;
    if (t < TN) out[t] = det[t] * __expf(-LOG_GAMMA * (float)t * INV_SR);
}

// ---------------- launch ----------------

extern "C" void kernel_launch(void* const* d_in, const int* in_sizes, int n_in,
                              void* d_out, int out_size, void* d_ws, size_t ws_size,
                              hipStream_t stream) {
    const float* init_rad   = (const float*)d_in[0];
    const float* basis      = (const float*)d_in[1];
    const float* absorption = (const float*)d_in[2];
    const float* scattering = (const float*)d_in[3];
    const float* det_w      = (const float*)d_in[4];
    const int*   row        = (const int*)d_in[5];
    const int*   col        = (const int*)d_in[6];
    const int*   rid        = (const int*)d_in[7];
    const int*   delay      = (const int*)d_in[8];
    const int*   det_delay  = (const int*)d_in[9];
    float* out = (float*)d_out;

    char* ws = (char*)d_ws;
    size_t o = 0;
    auto alloc = [&](size_t bytes) {
        void* p = ws + o;
        o = (o + bytes + 255) & ~(size_t)255;
        return p;
    };
    int*    cnt    = (int*)alloc(RN * 4);
    int*    off    = (int*)alloc((RN + 1) * 4);
    int*    cursor = (int*)alloc(RN * 4);
    int*    packed = (int*)alloc(EN * 4);
    float*  kernv  = (float*)alloc(EN * 4);
    __half* bufA   = (__half*)alloc((size_t)RN * TN * 2);
    __half* bufB   = (__half*)alloc((size_t)RN * TN * 2);
    __half* tot    = (__half*)alloc((size_t)RN * TN * 2);
    float*  det    = (float*)alloc(TN * 4);

    hipMemsetAsync(cnt, 0, RN * 4, stream);
    hipMemsetAsync(det, 0, TN * 4, stream);

    hist_kernel<<<EN / 256, 256, 0, stream>>>(row, cnt);
    scan_kernel<<<1, 1024, 0, stream>>>(cnt, off, cursor);
    scatter_kernel<<<EN / 256, 256, 0, stream>>>(row, col, rid, delay, basis,
                                                 absorption, scattering, cursor,
                                                 packed, kernv);
    init_kernel<<<(RN * TN / 8 + 255) / 256, 256, 0, stream>>>(init_rad, bufA, tot);

    __half* cur = bufA;
    __half* nxt = bufB;
    for (int b = 0; b < NBOUNCE; ++b) {
        bounce_kernel<<<RN * NCHUNK, 192, 0, stream>>>(cur, nxt, tot, off, packed, kernv);
        __half* tmp = cur; cur = nxt; nxt = tmp;
    }

    detect_kernel<<<dim3(TN / 256, RN / 64), 256, 0, stream>>>(tot, det_w, det_delay, det);
    final_kernel<<<TN / 256, 256, 0, stream>>>(det, out);
}

// Round 4
// 697.902 us; speedup vs baseline: 1.9707x; 1.9707x over previous
//
#include <hip/hip_runtime.h>
#include <hip/hip_bf16.h>
#include <hip/hip_fp16.h>

#define RN 4096
#define EN 131072
#define TN 1536
#define T2 768            // sample-pairs per row
#define SP 1040           // padded row stride in pairs (16B-aligned, > 1025)
#define PADP 257          // front wrap-replica pairs
#define PN 256
#define NBOUNCE 12
#define NCHUNK 4
#define CP 192            // pairs per chunk
// np.float32(np.log(1e-3))
#define LOG_GAMMA -6.90775528f
#define INV_SR (1.0f / 16000.0f)

// ---------------- CSR build ----------------

__global__ void hist_kernel(const int* __restrict__ row, int* __restrict__ cnt) {
    int e = blockIdx.x * blockDim.x + threadIdx.x;
    if (e < EN) atomicAdd(&cnt[row[e]], 1);
}

// single block, 1024 threads: exclusive scan of cnt[0..RN) -> off[0..RN], off[RN]=EN
__global__ void scan_kernel(const int* __restrict__ cnt, int* __restrict__ off,
                            int* __restrict__ cursor) {
    __shared__ int part[1024];
    int tid = threadIdx.x;
    int v0 = cnt[tid * 4 + 0], v1 = cnt[tid * 4 + 1];
    int v2 = cnt[tid * 4 + 2], v3 = cnt[tid * 4 + 3];
    part[tid] = v0 + v1 + v2 + v3;
    __syncthreads();
    for (int ofs = 1; ofs < 1024; ofs <<= 1) {
        int x = (tid >= ofs) ? part[tid - ofs] : 0;
        __syncthreads();
        part[tid] += x;
        __syncthreads();
    }
    int excl = (tid == 0) ? 0 : part[tid - 1];
    int o0 = excl, o1 = o0 + v0, o2 = o1 + v1, o3 = o2 + v2;
    off[tid * 4 + 0] = o0; cursor[tid * 4 + 0] = o0;
    off[tid * 4 + 1] = o1; cursor[tid * 4 + 1] = o1;
    off[tid * 4 + 2] = o2; cursor[tid * 4 + 2] = o2;
    off[tid * 4 + 3] = o3; cursor[tid * 4 + 3] = o3;
    if (tid == 1023) off[RN] = o3 + v3;
}

// per edge: kernel value + precomputed relative byte offset into the padded layout.
// md.x = ((col*SP + PADP - dpair) << 2) | (delay & 1),  md.y = bits(kern)
__global__ void scatter_kernel(const int* __restrict__ row, const int* __restrict__ col,
                               const int* __restrict__ rid, const int* __restrict__ delay,
                               const float* __restrict__ basis,
                               const float* __restrict__ absorption,
                               const float* __restrict__ scattering,
                               int* __restrict__ cursor, int2* __restrict__ mdarr) {
    int e = blockIdx.x * blockDim.x + threadIdx.x;
    if (e >= EN) return;
    int p = rid[e];
    float a = absorption[p];
    float s = scattering[p];
    float k = (1.0f - a) * (s * basis[e] + (1.0f - s) * basis[EN + e]);
    int d = delay[e];
    int dpair = (d + 1) >> 1;                       // d in [0,512)
    int off = ((col[e] * SP + PADP - dpair) << 2) | (d & 1);
    int pos = atomicAdd(&cursor[row[e]], 1);
    mdarr[pos] = make_int2(off, __float_as_int(k));
}

// ---------------- init: padded cur = tot = half(x * window) ----------------

__global__ __launch_bounds__(256) void init_kernel(const float* __restrict__ x,
                                                   __half* __restrict__ cur,
                                                   __half* __restrict__ tot) {
    int r = blockIdx.x;
    int tid = threadIdx.x;
    const float* xr = x + r * TN;
    uint* curp = (uint*)cur + (size_t)r * SP;
    uint* totp = (uint*)tot + (size_t)r * T2;
#pragma unroll
    for (int kk = 0; kk < 3; ++kk) {
        int q = tid + kk * 256;                     // pair index
        int t = q * 2;
        float wa = __expf(LOG_GAMMA * (float)t * INV_SR);
        float wb = __expf(LOG_GAMMA * (float)(t + 1) * INV_SR);
        __half2 h = __float22half2_rn(make_float2(xr[t] * wa, xr[t + 1] * wb));
        uint u = *(uint*)&h;
        curp[PADP + q] = u;
        if (q >= 511) curp[q - 511] = u;            // wrap replica
        totp[q] = u;
    }
}

// ---------------- bounce ----------------
// Block = (row r, chunk of 192 pairs), 64 threads (1 wave), 3 pairs/thread.
// blockIdx = r*4 + chunk -> round-robin XCD mapping gives chunk<->XCD L2 affinity.

__global__ __launch_bounds__(64) void bounce_kernel(
        const __half* __restrict__ cur, __half* __restrict__ nxt, __half* __restrict__ tot,
        const int* __restrict__ offs, const int2* __restrict__ mdarr) {
    int bid = blockIdx.x;
    int r = bid >> 2;
    int c0 = (bid & 3) * CP;
    int tid = threadIdx.x;
    int pb = c0 + tid;                              // base pair index (loop-invariant)
    int e0 = __builtin_amdgcn_readfirstlane(offs[r]);
    int e1 = __builtin_amdgcn_readfirstlane(offs[r + 1]);
    float a0 = 0.f, a1 = 0.f, a2 = 0.f, a3 = 0.f, a4 = 0.f, a5 = 0.f;
    const char* curb = (const char*)cur;

    int2 md = mdarr[e0];                            // mdarr has EN+1 entries
    for (int j = e0; j < e1; ++j) {
        int2 mdn = mdarr[j + 1];                    // prefetch next edge
        uint o  = __builtin_amdgcn_readfirstlane((uint)md.x);
        float k = __uint_as_float(__builtin_amdgcn_readfirstlane((uint)md.y));
        const uint* rp = (const uint*)(curb + (o & ~1u));
        if (o & 1) {                                // odd delay: realign by 16 bits
            uint w0 = rp[pb],       w0b = rp[pb + 1];
            uint w1 = rp[pb + 64],  w1b = rp[pb + 65];
            uint w2 = rp[pb + 128], w2b = rp[pb + 129];
            uint v0 = __builtin_amdgcn_alignbit(w0b, w0, 16);
            uint v1 = __builtin_amdgcn_alignbit(w1b, w1, 16);
            uint v2 = __builtin_amdgcn_alignbit(w2b, w2, 16);
            __half2 h0 = *(__half2*)&v0, h1 = *(__half2*)&v1, h2 = *(__half2*)&v2;
            a0 = fmaf(k, __half2float(h0.x), a0); a1 = fmaf(k, __half2float(h0.y), a1);
            a2 = fmaf(k, __half2float(h1.x), a2); a3 = fmaf(k, __half2float(h1.y), a3);
            a4 = fmaf(k, __half2float(h2.x), a4); a5 = fmaf(k, __half2float(h2.y), a5);
        } else {
            uint v0 = rp[pb], v1 = rp[pb + 64], v2 = rp[pb + 128];
            __half2 h0 = *(__half2*)&v0, h1 = *(__half2*)&v1, h2 = *(__half2*)&v2;
            a0 = fmaf(k, __half2float(h0.x), a0); a1 = fmaf(k, __half2float(h0.y), a1);
            a2 = fmaf(k, __half2float(h1.x), a2); a3 = fmaf(k, __half2float(h1.y), a3);
            a4 = fmaf(k, __half2float(h2.x), a4); a5 = fmaf(k, __half2float(h2.y), a5);
        }
        md = mdn;
    }

    uint* nxtp = (uint*)nxt + (size_t)r * SP;
    uint* totp = (uint*)tot + (size_t)r * T2;
    float ax[3] = {a0, a2, a4}, ay[3] = {a1, a3, a5};
#pragma unroll
    for (int kk = 0; kk < 3; ++kk) {
        int q = pb + kk * 64;
        __half2 h = __float22half2_rn(make_float2(ax[kk], ay[kk]));
        uint u = *(uint*)&h;
        nxtp[PADP + q] = u;
        if (q >= 511) nxtp[q - 511] = u;            // wrap replica
        uint tu = totp[q];
        __half2 tn = __hadd2(*(__half2*)&tu, h);
        totp[q] = *(uint*)&tn;
    }
}

// ---------------- detection ----------------

__global__ void detect_kernel(const __half* __restrict__ tot, const float* __restrict__ w,
                              const int* __restrict__ dd, float* __restrict__ det) {
    int t = blockIdx.x * 256 + threadIdx.x;
    int r0 = blockIdx.y * 64;
    float acc = 0.f;
    for (int r = r0; r < r0 + 64; ++r) {
        int d = dd[r];
        int idx = t - d;
        if (idx < 0) idx += TN;
        acc = fmaf(w[r], __half2float(tot[r * TN + idx]), acc);
    }
    atomicAdd(&det[t], acc);
}

__global__ void final_kernel(const float* __restrict__ det, float* __restrict__ out) {
    int t = blockIdx.x * 256 + threadIdx.x;
    if (t < TN) out[t] = det[t] * __expf(-LOG_GAMMA * (float)t * INV_SR);
}

// ---------------- launch ----------------

extern "C" void kernel_launch(void* const* d_in, const int* in_sizes, int n_in,
                              void* d_out, int out_size, void* d_ws, size_t ws_size,
                              hipStream_t stream) {
    const float* init_rad   = (const float*)d_in[0];
    const float* basis      = (const float*)d_in[1];
    const float* absorption = (const float*)d_in[2];
    const float* scattering = (const float*)d_in[3];
    const float* det_w      = (const float*)d_in[4];
    const int*   row        = (const int*)d_in[5];
    const int*   col        = (const int*)d_in[6];
    const int*   rid        = (const int*)d_in[7];
    const int*   delay      = (const int*)d_in[8];
    const int*   det_delay  = (const int*)d_in[9];
    float* out = (float*)d_out;

    char* ws = (char*)d_ws;
    size_t o = 0;
    auto alloc = [&](size_t bytes) {
        void* p = ws + o;
        o = (o + bytes + 255) & ~(size_t)255;
        return p;
    };
    int*    cnt    = (int*)alloc(RN * 4);
    int*    off    = (int*)alloc((RN + 1) * 4);
    int*    cursor = (int*)alloc(RN * 4);
    int2*   mdarr  = (int2*)alloc((size_t)(EN + 1) * 8);
    __half* bufA   = (__half*)alloc((size_t)RN * SP * 4);
    __half* bufB   = (__half*)alloc((size_t)RN * SP * 4);
    __half* tot    = (__half*)alloc((size_t)RN * T2 * 4);
    float*  det    = (float*)alloc(TN * 4);

    hipMemsetAsync(cnt, 0, RN * 4, stream);
    hipMemsetAsync(det, 0, TN * 4, stream);

    hist_kernel<<<EN / 256, 256, 0, stream>>>(row, cnt);
    scan_kernel<<<1, 1024, 0, stream>>>(cnt, off, cursor);
    scatter_kernel<<<EN / 256, 256, 0, stream>>>(row, col, rid, delay, basis,
                                                 absorption, scattering, cursor, mdarr);
    init_kernel<<<RN, 256, 0, stream>>>(init_rad, bufA, tot);

    __half* cur = bufA;
    __half* nxt = bufB;
    for (int b = 0; b < NBOUNCE; ++b) {
        bounce_kernel<<<RN * NCHUNK, 64, 0, stream>>>(cur, nxt, tot, off, mdarr);
        __half* tmp = cur; cur = nxt; nxt = tmp;
    }

    detect_kernel<<<dim3(TN / 256, RN / 64), 256, 0, stream>>>(tot, det_w, det_delay, det);
    final_kernel<<<TN / 256, 256, 0, stream>>>(det, out);
}